// Round 1
// baseline (497.547 us; speedup 1.0000x reference)
//
#include <hip/hip_runtime.h>
#include <stdint.h>
#include <stddef.h>

// ---------------- problem constants ----------------
#define SEQ   2048
#define BATCH 2
#define HID   2048
#define NH    16
#define HD    128
#define MTOT  (SEQ*BATCH)   // 4096
#define NQKV  (3*HID)       // 6144
#define KDIM  HID           // 2048

typedef short  bf16x8 __attribute__((ext_vector_type(8)));  // 8 bf16 in 4 VGPRs
typedef float  f32x4  __attribute__((ext_vector_type(4)));

__device__ __forceinline__ unsigned short f2bf(float f) {
  union { float f; uint32_t u; } a; a.f = f;
  uint32_t r = a.u + 0x7fffu + ((a.u >> 16) & 1u);   // RNE
  return (unsigned short)(r >> 16);
}

__device__ __forceinline__ f32x4 mfma16(bf16x8 a, bf16x8 b, f32x4 c) {
  return __builtin_amdgcn_mfma_f32_16x16x32_bf16(a, b, c, 0, 0, 0);
}

// ---------------- fp32 -> bf16 convert ----------------
__global__ void cvt_f32_bf16(const float* __restrict__ in,
                             unsigned short* __restrict__ out, int n4) {
  int i = blockIdx.x * blockDim.x + threadIdx.x;
  int stride = gridDim.x * blockDim.x;
  for (; i < n4; i += stride) {
    float4 f = reinterpret_cast<const float4*>(in)[i];
    ushort4 o;
    o.x = f2bf(f.x); o.y = f2bf(f.y); o.z = f2bf(f.z); o.w = f2bf(f.w);
    reinterpret_cast<ushort4*>(out)[i] = o;
  }
}

// ---------------- QKV GEMM: mixed = hs @ w_qkv^T + b; scatter to q/k/v ----------------
// A [4096][2048] bf16 row-major, B [6144][2048] bf16 row-major (B^T gemm).
// 128x128 tile, BK=32, 256 threads (4 waves, each 64x64 = 4x4 MFMA tiles).
__global__ __launch_bounds__(256, 2) void qkv_gemm(
    const unsigned short* __restrict__ A,
    const unsigned short* __restrict__ B,
    const float* __restrict__ bias,
    unsigned short* __restrict__ Qo,
    unsigned short* __restrict__ Ko,
    unsigned short* __restrict__ Vo)
{
  __shared__ unsigned short Ash[128][40];   // +8 pad: 2-way banks, 16B-aligned rows
  __shared__ unsigned short Bsh[128][40];
  const int t  = threadIdx.x;
  const int l  = t & 63;
  const int w  = t >> 6;
  const int wm = w >> 1, wn = w & 1;
  const int m0 = blockIdx.y * 128, n0 = blockIdx.x * 128;
  const int srow = t >> 2;            // 0..63
  const int scol = (t & 3) * 8;       // 0,8,16,24
  const unsigned short* Ap = A + (size_t)(m0 + srow) * KDIM + scol;
  const unsigned short* Bp = B + (size_t)(n0 + srow) * KDIM + scol;
  const int fr  = l & 15;
  const int fg8 = (l >> 4) * 8;

  f32x4 acc[4][4] = {};
  uint4 ra0 = *(const uint4*)(Ap);
  uint4 ra1 = *(const uint4*)(Ap + (size_t)64 * KDIM);
  uint4 rb0 = *(const uint4*)(Bp);
  uint4 rb1 = *(const uint4*)(Bp + (size_t)64 * KDIM);

  for (int kk = 0; kk < KDIM / 32; ++kk) {
    *(uint4*)&Ash[srow][scol]      = ra0;
    *(uint4*)&Ash[64 + srow][scol] = ra1;
    *(uint4*)&Bsh[srow][scol]      = rb0;
    *(uint4*)&Bsh[64 + srow][scol] = rb1;
    __syncthreads();
    if (kk < KDIM / 32 - 1) {
      const unsigned short* Ap2 = Ap + (kk + 1) * 32;
      const unsigned short* Bp2 = Bp + (kk + 1) * 32;
      ra0 = *(const uint4*)(Ap2);
      ra1 = *(const uint4*)(Ap2 + (size_t)64 * KDIM);
      rb0 = *(const uint4*)(Bp2);
      rb1 = *(const uint4*)(Bp2 + (size_t)64 * KDIM);
    }
    bf16x8 af[4], bfr[4];
#pragma unroll
    for (int m = 0; m < 4; ++m)
      af[m] = *(const bf16x8*)&Ash[wm * 64 + m * 16 + fr][fg8];
#pragma unroll
    for (int n = 0; n < 4; ++n)
      bfr[n] = *(const bf16x8*)&Bsh[wn * 64 + n * 16 + fr][fg8];
#pragma unroll
    for (int m = 0; m < 4; ++m)
#pragma unroll
      for (int n = 0; n < 4; ++n)
        acc[m][n] = mfma16(af[m], bfr[n], acc[m][n]);
    __syncthreads();
  }

  // epilogue: bias (+ q-scale fold) + scatter to [b][h][s][d] bf16
  const int g4 = (l >> 4) * 4;
#pragma unroll
  for (int n = 0; n < 4; ++n) {
    int ncol = n0 + wn * 64 + n * 16 + fr;
    float bv = bias[ncol];
    int head = ncol / 384;
    int rem  = ncol - head * 384;
    int wi   = rem >> 7;          // 0=q 1=k 2=v
    int d    = rem & 127;
    unsigned short* dst = (wi == 0) ? Qo : ((wi == 1) ? Ko : Vo);
#pragma unroll
    for (int m = 0; m < 4; ++m) {
#pragma unroll
      for (int j = 0; j < 4; ++j) {
        int r = m0 + wm * 64 + m * 16 + g4 + j;
        int s = r >> 1, bb = r & 1;
        float val = acc[m][n][j] + bv;
        if (wi == 0) val *= 0.08838834764831845f;   // fold 1/sqrt(128) into Q
        dst[(((size_t)(bb * NH + head)) * SEQ + s) * HD + d] = f2bf(val);
      }
    }
  }
}

// ---------------- causal flash attention ----------------
// grid (qt=32, bh=32); block 256 = 4 waves x 16 q-rows; KBLK=64.
__global__ __launch_bounds__(256, 2) void attn_fwd(
    const unsigned short* __restrict__ Q,
    const unsigned short* __restrict__ K,
    const unsigned short* __restrict__ V,
    unsigned short* __restrict__ ctx)
{
  __shared__ unsigned short Ksh[64][136];      // [key][d], +8 pad
  __shared__ unsigned short Vt[128][68];       // [d][key], +4 pad (8B-aligned rows)
  __shared__ unsigned short Psh[4][16][72];    // per-wave P tile [q][key], +8 pad
  const int t  = threadIdx.x, l = t & 63, w = t >> 6;
  const int qt = blockIdx.x;
  const int bh = blockIdx.y;                   // = b*16 + h
  const int fr = l & 15, fg = l >> 4;
  const size_t base = (size_t)bh * SEQ * HD;

  // Q fragments in registers (scale already folded in)
  bf16x8 qf[4];
  {
    const unsigned short* qp =
        Q + base + (size_t)(qt * 64 + w * 16 + fr) * HD + fg * 8;
#pragma unroll
    for (int c = 0; c < 4; ++c)
      qf[c] = *(const bf16x8*)(qp + c * 32);
  }
  f32x4 oacc[8] = {};
  float mrow[4] = {-1e30f, -1e30f, -1e30f, -1e30f};
  float lrow[4] = {0.f, 0.f, 0.f, 0.f};

  for (int kt = 0; kt <= qt; ++kt) {
    __syncthreads();
    { // stage K row-major, V transposed
      const int col = (t & 15) * 8;
#pragma unroll
      for (int c = 0; c < 4; ++c) {
        int row = c * 16 + (t >> 4);
        uint4 kv = *(const uint4*)(K + base + (size_t)(kt * 64 + row) * HD + col);
        *(uint4*)&Ksh[row][col] = kv;
        uint4 vv = *(const uint4*)(V + base + (size_t)(kt * 64 + row) * HD + col);
        const unsigned short* vs = (const unsigned short*)&vv;
#pragma unroll
        for (int i = 0; i < 8; ++i)
          Vt[col + i][row] = vs[i];
      }
    }
    __syncthreads();

    // S = Q K^T  (16 q-rows x 64 keys per wave)
    f32x4 sacc[4] = {};
#pragma unroll
    for (int c = 0; c < 4; ++c) {
#pragma unroll
      for (int n = 0; n < 4; ++n) {
        bf16x8 kf = *(const bf16x8*)&Ksh[n * 16 + fr][c * 32 + fg * 8];
        sacc[n] = mfma16(qf[c], kf, sacc[n]);
      }
    }
    if (kt == qt) { // causal mask on diagonal tile
#pragma unroll
      for (int n = 0; n < 4; ++n)
#pragma unroll
        for (int j = 0; j < 4; ++j) {
          int colk = kt * 64 + n * 16 + fr;
          int rowq = qt * 64 + w * 16 + fg * 4 + j;
          if (colk > rowq) sacc[n][j] = -1e30f;
        }
    }
    // online softmax
    float tm[4];
#pragma unroll
    for (int j = 0; j < 4; ++j) {
      float v0 = fmaxf(fmaxf(sacc[0][j], sacc[1][j]),
                       fmaxf(sacc[2][j], sacc[3][j]));
      v0 = fmaxf(v0, __shfl_xor(v0, 1));
      v0 = fmaxf(v0, __shfl_xor(v0, 2));
      v0 = fmaxf(v0, __shfl_xor(v0, 4));
      v0 = fmaxf(v0, __shfl_xor(v0, 8));
      tm[j] = v0;
    }
    float scalej[4], psum[4];
#pragma unroll
    for (int j = 0; j < 4; ++j) {
      float mnew = fmaxf(mrow[j], tm[j]);
      scalej[j] = exp2f((mrow[j] - mnew) * 1.4426950408889634f);
      mrow[j] = mnew;
      psum[j] = 0.f;
    }
#pragma unroll
    for (int n = 0; n < 4; ++n)
#pragma unroll
      for (int j = 0; j < 4; ++j) {
        float p = exp2f((sacc[n][j] - mrow[j]) * 1.4426950408889634f);
        sacc[n][j] = p;
        psum[j] += p;
      }
#pragma unroll
    for (int j = 0; j < 4; ++j) {
      float s = psum[j];
      s += __shfl_xor(s, 1);
      s += __shfl_xor(s, 2);
      s += __shfl_xor(s, 4);
      s += __shfl_xor(s, 8);
      lrow[j] = lrow[j] * scalej[j] + s;
    }
#pragma unroll
    for (int n = 0; n < 8; ++n)
#pragma unroll
      for (int j = 0; j < 4; ++j)
        oacc[n][j] *= scalej[j];
    // P -> LDS (bf16), per-wave region (same-wave RAW, no barrier needed)
#pragma unroll
    for (int n = 0; n < 4; ++n)
#pragma unroll
      for (int j = 0; j < 4; ++j)
        Psh[w][fg * 4 + j][n * 16 + fr] = f2bf(sacc[n][j]);
    // O += P V
#pragma unroll
    for (int ks = 0; ks < 2; ++ks) {
      bf16x8 pf = *(const bf16x8*)&Psh[w][fr][ks * 32 + fg * 8];
#pragma unroll
      for (int n = 0; n < 8; ++n) {
        union { uint2 u[2]; bf16x8 v; } uv;
        uv.u[0] = *(const uint2*)&Vt[n * 16 + fr][ks * 32 + fg * 8];
        uv.u[1] = *(const uint2*)&Vt[n * 16 + fr][ks * 32 + fg * 8 + 4];
        oacc[n] = mfma16(pf, uv.v, oacc[n]);
      }
    }
  }

  // normalize + write ctx[(s*B+b)][h*128+d] bf16
  const int bb = bh >> 4, h = bh & 15;
  const int qrow_base = qt * 64 + w * 16;
#pragma unroll
  for (int n = 0; n < 8; ++n)
#pragma unroll
    for (int j = 0; j < 4; ++j) {
      int qrow = qrow_base + fg * 4 + j;
      float val = oacc[n][j] / lrow[j];
      ctx[((size_t)(qrow * BATCH + bb)) * HID + h * HD + n * 16 + fr] = f2bf(val);
    }
}

// ---------------- dense GEMM: out = ctx @ w_dense^T + b (fp32 out) ----------------
__global__ __launch_bounds__(256, 2) void dense_gemm(
    const unsigned short* __restrict__ A,
    const unsigned short* __restrict__ B,
    const float* __restrict__ bias,
    float* __restrict__ out)
{
  __shared__ unsigned short Ash[128][40];
  __shared__ unsigned short Bsh[128][40];
  const int t  = threadIdx.x;
  const int l  = t & 63;
  const int w  = t >> 6;
  const int wm = w >> 1, wn = w & 1;
  const int m0 = blockIdx.y * 128, n0 = blockIdx.x * 128;
  const int srow = t >> 2;
  const int scol = (t & 3) * 8;
  const unsigned short* Ap = A + (size_t)(m0 + srow) * KDIM + scol;
  const unsigned short* Bp = B + (size_t)(n0 + srow) * KDIM + scol;
  const int fr  = l & 15;
  const int fg8 = (l >> 4) * 8;

  f32x4 acc[4][4] = {};
  uint4 ra0 = *(const uint4*)(Ap);
  uint4 ra1 = *(const uint4*)(Ap + (size_t)64 * KDIM);
  uint4 rb0 = *(const uint4*)(Bp);
  uint4 rb1 = *(const uint4*)(Bp + (size_t)64 * KDIM);

  for (int kk = 0; kk < KDIM / 32; ++kk) {
    *(uint4*)&Ash[srow][scol]      = ra0;
    *(uint4*)&Ash[64 + srow][scol] = ra1;
    *(uint4*)&Bsh[srow][scol]      = rb0;
    *(uint4*)&Bsh[64 + srow][scol] = rb1;
    __syncthreads();
    if (kk < KDIM / 32 - 1) {
      const unsigned short* Ap2 = Ap + (kk + 1) * 32;
      const unsigned short* Bp2 = Bp + (kk + 1) * 32;
      ra0 = *(const uint4*)(Ap2);
      ra1 = *(const uint4*)(Ap2 + (size_t)64 * KDIM);
      rb0 = *(const uint4*)(Bp2);
      rb1 = *(const uint4*)(Bp2 + (size_t)64 * KDIM);
    }
    bf16x8 af[4], bfr[4];
#pragma unroll
    for (int m = 0; m < 4; ++m)
      af[m] = *(const bf16x8*)&Ash[wm * 64 + m * 16 + fr][fg8];
#pragma unroll
    for (int n = 0; n < 4; ++n)
      bfr[n] = *(const bf16x8*)&Bsh[wn * 64 + n * 16 + fr][fg8];
#pragma unroll
    for (int m = 0; m < 4; ++m)
#pragma unroll
      for (int n = 0; n < 4; ++n)
        acc[m][n] = mfma16(af[m], bfr[n], acc[m][n]);
    __syncthreads();
  }

  const int g4 = (l >> 4) * 4;
#pragma unroll
  for (int n = 0; n < 4; ++n) {
    int ncol = n0 + wn * 64 + n * 16 + fr;
    float bv = bias[ncol];
#pragma unroll
    for (int m = 0; m < 4; ++m) {
#pragma unroll
      for (int j = 0; j < 4; ++j) {
        int r = m0 + wm * 64 + m * 16 + g4 + j;
        out[(size_t)r * HID + ncol] = acc[m][n][j] + bv;
      }
    }
  }
}

// ---------------- launcher ----------------
extern "C" void kernel_launch(void* const* d_in, const int* in_sizes, int n_in,
                              void* d_out, int out_size, void* d_ws, size_t ws_size,
                              hipStream_t stream) {
  const float* hs      = (const float*)d_in[0];
  const float* w_qkv   = (const float*)d_in[1];
  const float* b_qkv   = (const float*)d_in[2];
  const float* w_dense = (const float*)d_in[3];
  const float* b_dense = (const float*)d_in[4];
  float* out = (float*)d_out;

  unsigned short* hsb = (unsigned short*)d_ws;              // 8,388,608
  unsigned short* wqb = hsb + (size_t)MTOT * HID;           // 12,582,912
  unsigned short* wdb = wqb + (size_t)NQKV * HID;           // 4,194,304
  unsigned short* q   = wdb + (size_t)HID * HID;            // 8,388,608
  unsigned short* k   = q   + (size_t)MTOT * HID;
  unsigned short* v   = k   + (size_t)MTOT * HID;
  unsigned short* ctx = v   + (size_t)MTOT * HID;           // 8,388,608

  cvt_f32_bf16<<<2048, 256, 0, stream>>>(hs,      hsb, (MTOT * HID) / 4);
  cvt_f32_bf16<<<2048, 256, 0, stream>>>(w_qkv,   wqb, (NQKV * HID) / 4);
  cvt_f32_bf16<<<1024, 256, 0, stream>>>(w_dense, wdb, (HID * HID) / 4);

  qkv_gemm<<<dim3(NQKV / 128, MTOT / 128), 256, 0, stream>>>(hsb, wqb, b_qkv, q, k, v);
  attn_fwd<<<dim3(SEQ / 64, BATCH * NH), 256, 0, stream>>>(q, k, v, ctx);
  dense_gemm<<<dim3(HID / 128, MTOT / 128), 256, 0, stream>>>(ctx, wdb, b_dense, out);
}

// Round 2
// 308.054 us; speedup vs baseline: 1.6151x; 1.6151x over previous
//
#include <hip/hip_runtime.h>
#include <stdint.h>
#include <stddef.h>

// ---------------- problem constants ----------------
#define SEQ   2048
#define BATCH 2
#define HID   2048
#define NH    16
#define HD    128
#define MTOT  (SEQ*BATCH)   // 4096
#define NQKV  (3*HID)       // 6144
#define KDIM  HID           // 2048
#define LOG2E 1.4426950408889634f

typedef short  bf16x8 __attribute__((ext_vector_type(8)));  // 8 bf16 in 4 VGPRs
typedef float  f32x4  __attribute__((ext_vector_type(4)));

__device__ __forceinline__ unsigned short f2bf(float f) {
  union { float f; uint32_t u; } a; a.f = f;
  uint32_t r = a.u + 0x7fffu + ((a.u >> 16) & 1u);   // RNE
  return (unsigned short)(r >> 16);
}

__device__ __forceinline__ f32x4 mfma16(bf16x8 a, bf16x8 b, f32x4 c) {
  return __builtin_amdgcn_mfma_f32_16x16x32_bf16(a, b, c, 0, 0, 0);
}

// async global->LDS, 16B per lane; LDS dest = uniform base + lane*16
__device__ __forceinline__ void gl_lds16(const unsigned short* g, unsigned short* l) {
  __builtin_amdgcn_global_load_lds(
      (const __attribute__((address_space(1))) void*)g,
      (__attribute__((address_space(3))) void*)l, 16, 0, 0);
}

// ---------------- fp32 -> bf16 convert ----------------
__global__ void cvt_f32_bf16(const float* __restrict__ in,
                             unsigned short* __restrict__ out, int n4) {
  int i = blockIdx.x * blockDim.x + threadIdx.x;
  int stride = gridDim.x * blockDim.x;
  for (; i < n4; i += stride) {
    float4 f = reinterpret_cast<const float4*>(in)[i];
    ushort4 o;
    o.x = f2bf(f.x); o.y = f2bf(f.y); o.z = f2bf(f.z); o.w = f2bf(f.w);
    reinterpret_cast<ushort4*>(out)[i] = o;
  }
}

// ---------------- V transpose: [bh][s][d] -> [bh][d][s] ----------------
__global__ __launch_bounds__(256) void transpose_v(
    const unsigned short* __restrict__ V, unsigned short* __restrict__ Vt) {
  __shared__ unsigned short tile[64][72];
  const int t  = threadIdx.x;
  const int bh = blockIdx.z;
  const int s0 = blockIdx.x * 64;
  const int d0 = blockIdx.y * 64;
  const size_t vb = (size_t)bh * SEQ * HD;
  const size_t tb = (size_t)bh * HD * SEQ;
#pragma unroll
  for (int p = 0; p < 2; ++p) {
    int r = p * 32 + (t >> 3);
    *(uint4*)&tile[r][(t & 7) * 8] =
        *(const uint4*)&V[vb + (size_t)(s0 + r) * HD + d0 + (t & 7) * 8];
  }
  __syncthreads();
#pragma unroll
  for (int p = 0; p < 2; ++p) {
    int dr = p * 32 + (t >> 3);
    int sc = (t & 7) * 8;
    unsigned short tmp[8];
#pragma unroll
    for (int e = 0; e < 8; ++e) tmp[e] = tile[sc + e][dr];
    *(uint4*)&Vt[tb + (size_t)(d0 + dr) * SEQ + s0 + sc] = *(const uint4*)tmp;
  }
}

// ---------------- QKV GEMM (m97-style: global_load_lds + swizzled reads) ----------------
// A [4096][2048] bf16, B [6144][2048] bf16 row-major (B^T gemm). 128x128 tile, BK=32.
__global__ __launch_bounds__(256, 3) void qkv_gemm(
    const unsigned short* __restrict__ A,
    const unsigned short* __restrict__ B,
    const float* __restrict__ bias,
    unsigned short* __restrict__ Qo,
    unsigned short* __restrict__ Ko,
    unsigned short* __restrict__ Vo)
{
  __shared__ unsigned short Ash[128 * 32];   // linear; LDS[row][x] = glob[row][x^(row&3)] (16B granules)
  __shared__ unsigned short Bsh[128 * 32];
  const int t = threadIdx.x, l = t & 63, w = t >> 6;
  const int wm = w >> 1, wn = w & 1;
  // bijective XCD swizzle (nwg % 8 == 0)
  int nwg = gridDim.x * gridDim.y;
  int id  = blockIdx.y * gridDim.x + blockIdx.x;
  int swz = (id & 7) * (nwg >> 3) + (id >> 3);
  const int m0 = (swz / gridDim.x) * 128, n0 = (swz % gridDim.x) * 128;
  const int fr = l & 15, fg = l >> 4;

  f32x4 acc[4][4] = {};
  for (int kk = 0; kk < KDIM / 32; ++kk) {
    const unsigned short* Akk = A + kk * 32;
    const unsigned short* Bkk = B + kk * 32;
#pragma unroll
    for (int i = 0; i < 2; ++i) {
      int ch  = w * 2 + i;                 // 8 chunks of 1KB per matrix
      int row = ch * 16 + (l >> 2);
      int c16 = (l & 3) ^ (row & 3);
      gl_lds16(Akk + (size_t)(m0 + row) * KDIM + c16 * 8, &Ash[ch * 512]);
      gl_lds16(Bkk + (size_t)(n0 + row) * KDIM + c16 * 8, &Bsh[ch * 512]);
    }
    __syncthreads();
    bf16x8 af[4], bfr[4];
#pragma unroll
    for (int m = 0; m < 4; ++m) {
      int row = wm * 64 + m * 16 + fr;
      af[m] = *(const bf16x8*)&Ash[row * 32 + ((fg ^ (row & 3)) * 8)];
    }
#pragma unroll
    for (int n = 0; n < 4; ++n) {
      int row = wn * 64 + n * 16 + fr;
      bfr[n] = *(const bf16x8*)&Bsh[row * 32 + ((fg ^ (row & 3)) * 8)];
    }
#pragma unroll
    for (int m = 0; m < 4; ++m)
#pragma unroll
      for (int n = 0; n < 4; ++n)
        acc[m][n] = mfma16(af[m], bfr[n], acc[m][n]);
    __syncthreads();
  }

  const int g4 = (l >> 4) * 4;
#pragma unroll
  for (int n = 0; n < 4; ++n) {
    int ncol = n0 + wn * 64 + n * 16 + fr;
    float bv = bias[ncol];
    int head = ncol / 384;
    int rem  = ncol - head * 384;
    int wi   = rem >> 7;          // 0=q 1=k 2=v
    int d    = rem & 127;
    unsigned short* dst = (wi == 0) ? Qo : ((wi == 1) ? Ko : Vo);
#pragma unroll
    for (int m = 0; m < 4; ++m) {
#pragma unroll
      for (int j = 0; j < 4; ++j) {
        int r = m0 + wm * 64 + m * 16 + g4 + j;
        int s = r >> 1, bb = r & 1;
        float val = acc[m][n][j] + bv;
        if (wi == 0) val *= 0.08838834764831845f;   // fold 1/sqrt(128) into Q
        dst[(((size_t)(bb * NH + head)) * SEQ + s) * HD + d] = f2bf(val);
      }
    }
  }
}

// ---------------- causal flash attention, paired q-tiles ----------------
// grid (16 pairs, 32 bh); block 256 = 4 waves x 16 q-rows per tile.
// Block handles q-tiles {pair, 31-pair}: exactly 33 tile-computes each.
__global__ __launch_bounds__(256, 2) void attn_fwd(
    const unsigned short* __restrict__ Q,
    const unsigned short* __restrict__ K,
    const unsigned short* __restrict__ Vt,   // [bh][d][s]
    unsigned short* __restrict__ ctx)
{
  __shared__ unsigned short Ksh[2][64 * 128];   // swizzled granules, 16KB each
  __shared__ unsigned short Vsh[2][128 * 64];   // [d][key] swizzled, 16KB each
  __shared__ unsigned short Psh[4][16 * 72];    // per-wave P tile
  const int t = threadIdx.x, l = t & 63, w = t >> 6;
  int nwg = gridDim.x * gridDim.y;              // 512
  int id  = blockIdx.y * gridDim.x + blockIdx.x;
  int swz = (id & 7) * (nwg >> 3) + (id >> 3);
  const int pair = swz & 15;
  const int bh   = swz >> 4;
  const int qtA = pair, qtB = 31 - pair;
  const int fr = l & 15, fg = l >> 4;
  const size_t base  = (size_t)bh * SEQ * HD;
  const size_t vbase = (size_t)bh * HD * SEQ;

#define STAGE(BUF, KT) do {                                                   \
    const unsigned short* Kt_ = K + base + (size_t)((KT) * 64) * HD;          \
    _Pragma("unroll")                                                         \
    for (int i_ = 0; i_ < 4; ++i_) {                                          \
      int ch_  = w * 4 + i_;                                                  \
      int row_ = ch_ * 4 + (l >> 4);                                          \
      int c16_ = (l & 15) ^ (row_ & 7);                                       \
      gl_lds16(Kt_ + (size_t)row_ * HD + c16_ * 8, &Ksh[BUF][ch_ * 512]);     \
    }                                                                         \
    const unsigned short* Vg_ = Vt + vbase + (KT) * 64;                       \
    _Pragma("unroll")                                                         \
    for (int i_ = 0; i_ < 4; ++i_) {                                          \
      int ch_  = w * 4 + i_;                                                  \
      int row_ = ch_ * 8 + (l >> 3);                                          \
      int c16_ = (l & 7) ^ (row_ & 7);                                        \
      gl_lds16(Vg_ + (size_t)row_ * SEQ + c16_ * 8, &Vsh[BUF][ch_ * 512]);    \
    }                                                                         \
  } while (0)

#define COMPUTE_TILE(QF, OACC, MROW, LROW, QT) do {                           \
    f32x4 sacc[4] = {};                                                       \
    _Pragma("unroll")                                                         \
    for (int c_ = 0; c_ < 4; ++c_) {                                          \
      _Pragma("unroll")                                                       \
      for (int n_ = 0; n_ < 4; ++n_) {                                        \
        int krow = n_ * 16 + fr;                                              \
        int g_   = (c_ * 4 + fg) ^ (krow & 7);                                \
        bf16x8 kf = *(const bf16x8*)&Ksh[buf][krow * 128 + g_ * 8];           \
        sacc[n_] = mfma16(QF[c_], kf, sacc[n_]);                              \
      }                                                                       \
    }                                                                         \
    if (kt == (QT)) {                                                         \
      _Pragma("unroll")                                                       \
      for (int n_ = 0; n_ < 4; ++n_)                                          \
        _Pragma("unroll")                                                     \
        for (int j_ = 0; j_ < 4; ++j_)                                        \
          if (n_ * 16 + fr > w * 16 + fg * 4 + j_) sacc[n_][j_] = -1e30f;     \
    }                                                                         \
    float tm_[4];                                                             \
    _Pragma("unroll")                                                         \
    for (int j_ = 0; j_ < 4; ++j_) {                                          \
      float v0 = fmaxf(fmaxf(sacc[0][j_], sacc[1][j_]),                       \
                       fmaxf(sacc[2][j_], sacc[3][j_]));                      \
      v0 = fmaxf(v0, __shfl_xor(v0, 1));                                      \
      v0 = fmaxf(v0, __shfl_xor(v0, 2));                                      \
      v0 = fmaxf(v0, __shfl_xor(v0, 4));                                      \
      v0 = fmaxf(v0, __shfl_xor(v0, 8));                                      \
      tm_[j_] = v0;                                                           \
    }                                                                         \
    float sc_[4], ps_[4];                                                     \
    _Pragma("unroll")                                                         \
    for (int j_ = 0; j_ < 4; ++j_) {                                          \
      float mn_ = fmaxf(MROW[j_], tm_[j_]);                                   \
      sc_[j_] = exp2f((MROW[j_] - mn_) * LOG2E);                              \
      MROW[j_] = mn_;                                                         \
      ps_[j_] = 0.f;                                                          \
    }                                                                         \
    _Pragma("unroll")                                                         \
    for (int n_ = 0; n_ < 4; ++n_)                                            \
      _Pragma("unroll")                                                       \
      for (int j_ = 0; j_ < 4; ++j_) {                                        \
        float p_ = exp2f((sacc[n_][j_] - MROW[j_]) * LOG2E);                  \
        sacc[n_][j_] = p_;                                                    \
        ps_[j_] += p_;                                                        \
      }                                                                       \
    _Pragma("unroll")                                                         \
    for (int j_ = 0; j_ < 4; ++j_) {                                          \
      float s_ = ps_[j_];                                                     \
      s_ += __shfl_xor(s_, 1);                                                \
      s_ += __shfl_xor(s_, 2);                                                \
      s_ += __shfl_xor(s_, 4);                                                \
      s_ += __shfl_xor(s_, 8);                                                \
      LROW[j_] = LROW[j_] * sc_[j_] + s_;                                     \
    }                                                                         \
    _Pragma("unroll")                                                         \
    for (int n_ = 0; n_ < 8; ++n_)                                            \
      _Pragma("unroll")                                                       \
      for (int j_ = 0; j_ < 4; ++j_)                                          \
        OACC[n_][j_] *= sc_[j_];                                              \
    _Pragma("unroll")                                                         \
    for (int n_ = 0; n_ < 4; ++n_)                                            \
      _Pragma("unroll")                                                       \
      for (int j_ = 0; j_ < 4; ++j_)                                          \
        Psh[w][(fg * 4 + j_) * 72 + n_ * 16 + fr] = f2bf(sacc[n_][j_]);       \
    _Pragma("unroll")                                                         \
    for (int ks_ = 0; ks_ < 2; ++ks_) {                                       \
      bf16x8 pf = *(const bf16x8*)&Psh[w][fr * 72 + ks_ * 32 + fg * 8];       \
      _Pragma("unroll")                                                       \
      for (int n_ = 0; n_ < 8; ++n_) {                                        \
        int vrow = n_ * 16 + fr;                                              \
        int g_   = (ks_ * 4 + fg) ^ (vrow & 7);                               \
        bf16x8 vf = *(const bf16x8*)&Vsh[buf][vrow * 64 + g_ * 8];            \
        OACC[n_] = mfma16(pf, vf, OACC[n_]);                                  \
      }                                                                       \
    }                                                                         \
  } while (0)

  // Q fragments for both tiles (scale folded in at QKV epilogue)
  bf16x8 qfA[4], qfB[4];
  {
    const unsigned short* qpA = Q + base + (size_t)(qtA * 64 + w * 16 + fr) * HD + fg * 8;
    const unsigned short* qpB = Q + base + (size_t)(qtB * 64 + w * 16 + fr) * HD + fg * 8;
#pragma unroll
    for (int c = 0; c < 4; ++c) {
      qfA[c] = *(const bf16x8*)(qpA + c * 32);
      qfB[c] = *(const bf16x8*)(qpB + c * 32);
    }
  }
  f32x4 oaccA[8] = {}, oaccB[8] = {};
  float mA[4] = {-1e30f, -1e30f, -1e30f, -1e30f};
  float mB[4] = {-1e30f, -1e30f, -1e30f, -1e30f};
  float lA[4] = {0.f, 0.f, 0.f, 0.f};
  float lB[4] = {0.f, 0.f, 0.f, 0.f};

  STAGE(0, 0);
  __syncthreads();
  int buf = 0;
  for (int kt = 0; kt <= qtB; ++kt) {
    if (kt < qtB) STAGE(buf ^ 1, kt + 1);       // prefetch hides under compute
    COMPUTE_TILE(qfB, oaccB, mB, lB, qtB);
    if (kt <= qtA) COMPUTE_TILE(qfA, oaccA, mA, lA, qtA);
    __syncthreads();                            // drains vmcnt -> next buf ready
    buf ^= 1;
  }

  const int bb = bh >> 4, h = bh & 15;
#define WRITE_CTX(OACC, LROW, QT) do {                                        \
    _Pragma("unroll")                                                         \
    for (int n_ = 0; n_ < 8; ++n_)                                            \
      _Pragma("unroll")                                                       \
      for (int j_ = 0; j_ < 4; ++j_) {                                        \
        int qrow = (QT) * 64 + w * 16 + fg * 4 + j_;                          \
        float val = OACC[n_][j_] / LROW[j_];                                  \
        ctx[((size_t)(qrow * BATCH + bb)) * HID + h * HD + n_ * 16 + fr] =    \
            f2bf(val);                                                        \
      }                                                                       \
  } while (0)
  WRITE_CTX(oaccA, lA, qtA);
  WRITE_CTX(oaccB, lB, qtB);
#undef STAGE
#undef COMPUTE_TILE
#undef WRITE_CTX
}

// ---------------- dense GEMM: out = ctx @ w_dense^T + b (fp32 out) ----------------
__global__ __launch_bounds__(256, 3) void dense_gemm(
    const unsigned short* __restrict__ A,
    const unsigned short* __restrict__ B,
    const float* __restrict__ bias,
    float* __restrict__ out)
{
  __shared__ unsigned short Ash[128 * 32];
  __shared__ unsigned short Bsh[128 * 32];
  const int t = threadIdx.x, l = t & 63, w = t >> 6;
  const int wm = w >> 1, wn = w & 1;
  int nwg = gridDim.x * gridDim.y;
  int id  = blockIdx.y * gridDim.x + blockIdx.x;
  int swz = (id & 7) * (nwg >> 3) + (id >> 3);
  const int m0 = (swz / gridDim.x) * 128, n0 = (swz % gridDim.x) * 128;
  const int fr = l & 15, fg = l >> 4;

  f32x4 acc[4][4] = {};
  for (int kk = 0; kk < KDIM / 32; ++kk) {
    const unsigned short* Akk = A + kk * 32;
    const unsigned short* Bkk = B + kk * 32;
#pragma unroll
    for (int i = 0; i < 2; ++i) {
      int ch  = w * 2 + i;
      int row = ch * 16 + (l >> 2);
      int c16 = (l & 3) ^ (row & 3);
      gl_lds16(Akk + (size_t)(m0 + row) * KDIM + c16 * 8, &Ash[ch * 512]);
      gl_lds16(Bkk + (size_t)(n0 + row) * KDIM + c16 * 8, &Bsh[ch * 512]);
    }
    __syncthreads();
    bf16x8 af[4], bfr[4];
#pragma unroll
    for (int m = 0; m < 4; ++m) {
      int row = wm * 64 + m * 16 + fr;
      af[m] = *(const bf16x8*)&Ash[row * 32 + ((fg ^ (row & 3)) * 8)];
    }
#pragma unroll
    for (int n = 0; n < 4; ++n) {
      int row = wn * 64 + n * 16 + fr;
      bfr[n] = *(const bf16x8*)&Bsh[row * 32 + ((fg ^ (row & 3)) * 8)];
    }
#pragma unroll
    for (int m = 0; m < 4; ++m)
#pragma unroll
      for (int n = 0; n < 4; ++n)
        acc[m][n] = mfma16(af[m], bfr[n], acc[m][n]);
    __syncthreads();
  }

  const int g4 = (l >> 4) * 4;
#pragma unroll
  for (int n = 0; n < 4; ++n) {
    int ncol = n0 + wn * 64 + n * 16 + fr;
    float bv = bias[ncol];
#pragma unroll
    for (int m = 0; m < 4; ++m) {
#pragma unroll
      for (int j = 0; j < 4; ++j) {
        int r = m0 + wm * 64 + m * 16 + g4 + j;
        out[(size_t)r * HID + ncol] = acc[m][n][j] + bv;
      }
    }
  }
}

// ---------------- launcher ----------------
extern "C" void kernel_launch(void* const* d_in, const int* in_sizes, int n_in,
                              void* d_out, int out_size, void* d_ws, size_t ws_size,
                              hipStream_t stream) {
  const float* hs      = (const float*)d_in[0];
  const float* w_qkv   = (const float*)d_in[1];
  const float* b_qkv   = (const float*)d_in[2];
  const float* w_dense = (const float*)d_in[3];
  const float* b_dense = (const float*)d_in[4];
  float* out = (float*)d_out;

  unsigned short* hsb = (unsigned short*)d_ws;              // 8.4M shorts
  unsigned short* wqb = hsb + (size_t)MTOT * HID;
  unsigned short* wdb = wqb + (size_t)NQKV * HID;
  unsigned short* q   = wdb + (size_t)HID * HID;
  unsigned short* k   = q   + (size_t)MTOT * HID;
  unsigned short* v   = k   + (size_t)MTOT * HID;
  unsigned short* ctx = v   + (size_t)MTOT * HID;
  unsigned short* vt  = hsb;   // alias: hsb is dead after qkv_gemm, vt written before attn

  cvt_f32_bf16<<<2048, 256, 0, stream>>>(hs,      hsb, (MTOT * HID) / 4);
  cvt_f32_bf16<<<2048, 256, 0, stream>>>(w_qkv,   wqb, (NQKV * HID) / 4);
  cvt_f32_bf16<<<1024, 256, 0, stream>>>(w_dense, wdb, (HID * HID) / 4);

  qkv_gemm<<<dim3(NQKV / 128, MTOT / 128), 256, 0, stream>>>(hsb, wqb, b_qkv, q, k, v);
  transpose_v<<<dim3(SEQ / 64, HD / 64, BATCH * NH), 256, 0, stream>>>(v, vt);
  attn_fwd<<<dim3(16, 32), 256, 0, stream>>>(q, k, vt, ctx);
  dense_gemm<<<dim3(HID / 128, MTOT / 128), 256, 0, stream>>>(ctx, wdb, b_dense, out);
}

// Round 3
// 293.013 us; speedup vs baseline: 1.6980x; 1.0513x over previous
//
#include <hip/hip_runtime.h>
#include <stdint.h>
#include <stddef.h>

// ---------------- problem constants ----------------
#define SEQ   2048
#define BATCH 2
#define HID   2048
#define NH    16
#define HD    128
#define MTOT  (SEQ*BATCH)   // 4096
#define NQKV  (3*HID)       // 6144
#define KDIM  HID           // 2048
#define LOG2E 1.4426950408889634f

#define BK      32
#define NTILES  (KDIM/BK)   // 64

typedef short  bf16x8 __attribute__((ext_vector_type(8)));  // 8 bf16 in 4 VGPRs
typedef float  f32x4  __attribute__((ext_vector_type(4)));

__device__ __forceinline__ unsigned short f2bf(float f) {
  union { float f; uint32_t u; } a; a.f = f;
  uint32_t r = a.u + 0x7fffu + ((a.u >> 16) & 1u);   // RNE
  return (unsigned short)(r >> 16);
}

__device__ __forceinline__ f32x4 mfma16(bf16x8 a, bf16x8 b, f32x4 c) {
  return __builtin_amdgcn_mfma_f32_16x16x32_bf16(a, b, c, 0, 0, 0);
}

// async global->LDS, 16B per lane; LDS dest = wave-uniform base + lane*16
__device__ __forceinline__ void gl_lds16(const unsigned short* g, unsigned short* l) {
  __builtin_amdgcn_global_load_lds(
      (const __attribute__((address_space(1))) void*)g,
      (__attribute__((address_space(3))) void*)l, 16, 0, 0);
}

// ---------------- fp32 -> bf16 convert ----------------
__global__ void cvt_f32_bf16(const float* __restrict__ in,
                             unsigned short* __restrict__ out, int n4) {
  int i = blockIdx.x * blockDim.x + threadIdx.x;
  int stride = gridDim.x * blockDim.x;
  for (; i < n4; i += stride) {
    float4 f = reinterpret_cast<const float4*>(in)[i];
    ushort4 o;
    o.x = f2bf(f.x); o.y = f2bf(f.y); o.z = f2bf(f.z); o.w = f2bf(f.w);
    reinterpret_cast<ushort4*>(out)[i] = o;
  }
}

// ---------------- V transpose: [bh][s][d] -> [bh][d][s] ----------------
__global__ __launch_bounds__(256) void transpose_v(
    const unsigned short* __restrict__ V, unsigned short* __restrict__ Vt) {
  __shared__ unsigned short tile[64][72];
  const int t  = threadIdx.x;
  const int bh = blockIdx.z;
  const int s0 = blockIdx.x * 64;
  const int d0 = blockIdx.y * 64;
  const size_t vb = (size_t)bh * SEQ * HD;
  const size_t tb = (size_t)bh * HD * SEQ;
#pragma unroll
  for (int p = 0; p < 2; ++p) {
    int r = p * 32 + (t >> 3);
    *(uint4*)&tile[r][(t & 7) * 8] =
        *(const uint4*)&V[vb + (size_t)(s0 + r) * HD + d0 + (t & 7) * 8];
  }
  __syncthreads();
#pragma unroll
  for (int p = 0; p < 2; ++p) {
    int dr = p * 32 + (t >> 3);
    int sc = (t & 7) * 8;
    unsigned short tmp[8];
#pragma unroll
    for (int e = 0; e < 8; ++e) tmp[e] = tile[sc + e][dr];
    *(uint4*)&Vt[tb + (size_t)(d0 + dr) * SEQ + s0 + sc] = *(const uint4*)tmp;
  }
}

// =====================================================================
// Deep-pipelined GEMM template pieces (BM=256, BN=128, BK=32, 512 thr).
// LDS rotation: 4 buffers x 24KB (A 16KB + B 8KB). Prefetch depth 3.
// Per K-tile phase: issue 3 gload_lds (tile kt+3) -> 8 ds_read_b128 ->
// vmcnt(6) -> s_barrier -> lgkmcnt(0) -> 16 MFMA -> s_barrier.
// Swizzle: LDS[r][g'] = glob[r][g'^(r&3)] (granules of 8 bf16), so both
// stage-source and frag-read apply g ^= (r&3): conflict-free reads.
// =====================================================================

#define GEMM_PRE()                                                            \
  const int t = threadIdx.x, l = t & 63, w = t >> 6;                          \
  const int wm = w >> 1, wn = w & 1;                                          \
  const int fr = l & 15, fg = l >> 4;                                         \
  const int sg = ((l & 3) ^ ((l >> 2) & 3)) * 8;                              \
  const int sr = (w * 16) + (l >> 2);                                         \
  const unsigned short* Aw = A + (size_t)(m0 + sr) * KDIM + sg;               \
  const unsigned short* Bw = B + (size_t)(n0 + sr) * KDIM + sg;               \
  const int aoff = (wm * 64 + fr) * 32 + ((fg ^ (fr & 3)) * 8);               \
  const int boff = 8192 + (wn * 64 + fr) * 32 + ((fg ^ (fr & 3)) * 8);        \
  f32x4 acc[4][4] = {};

#define STAGE_AB(KT) do {                                                     \
    unsigned short* dst = sm[(KT) & 3];                                       \
    const unsigned short* ap = Aw + (size_t)(KT) * BK;                        \
    gl_lds16(ap,                      &dst[w * 512]);                         \
    gl_lds16(ap + (size_t)128 * KDIM, &dst[4096 + w * 512]);                  \
    gl_lds16(Bw + (size_t)(KT) * BK,  &dst[8192 + w * 512]);                  \
  } while (0)

#define GEMM_BODY(KT, VM, DOSTAGE) do {                                       \
    const unsigned short* sb = sm[(KT) & 3];                                  \
    if (DOSTAGE) STAGE_AB((KT) + 3);                                          \
    bf16x8 af[4], bf[4];                                                      \
    _Pragma("unroll")                                                         \
    for (int m_ = 0; m_ < 4; ++m_)                                            \
      af[m_] = *(const bf16x8*)&sb[aoff + m_ * 512];                          \
    _Pragma("unroll")                                                         \
    for (int n_ = 0; n_ < 4; ++n_)                                            \
      bf[n_] = *(const bf16x8*)&sb[boff + n_ * 512];                          \
    asm volatile("s_waitcnt vmcnt(" #VM ")" ::: "memory");                    \
    asm volatile("s_barrier" ::: "memory");                                   \
    asm volatile("s_waitcnt lgkmcnt(0)" ::: "memory");                        \
    __builtin_amdgcn_sched_barrier(0);                                        \
    __builtin_amdgcn_s_setprio(1);                                            \
    _Pragma("unroll")                                                         \
    for (int m_ = 0; m_ < 4; ++m_)                                            \
      _Pragma("unroll")                                                       \
      for (int n_ = 0; n_ < 4; ++n_)                                          \
        acc[m_][n_] = mfma16(af[m_], bf[n_], acc[m_][n_]);                    \
    __builtin_amdgcn_sched_barrier(0);                                        \
    __builtin_amdgcn_s_setprio(0);                                            \
    asm volatile("s_barrier" ::: "memory");                                   \
  } while (0)

#define GEMM_MAIN()                                                           \
  STAGE_AB(0); STAGE_AB(1); STAGE_AB(2);                                      \
  asm volatile("s_waitcnt vmcnt(6)" ::: "memory");                            \
  asm volatile("s_barrier" ::: "memory");                                     \
  _Pragma("unroll 1")                                                         \
  for (int kt = 0; kt < NTILES - 3; ++kt)                                     \
    GEMM_BODY(kt, 6, 1);                                                      \
  GEMM_BODY(NTILES - 3, 3, 0);                                                \
  GEMM_BODY(NTILES - 2, 0, 0);                                                \
  GEMM_BODY(NTILES - 1, 0, 0);

// ---------------- QKV GEMM + scatter epilogue ----------------
// grid: 768 blocks (16 m-blocks x 48 n-blocks), XCD-swizzled.
__global__ __launch_bounds__(512, 1) void qkv_gemm(
    const unsigned short* __restrict__ A,
    const unsigned short* __restrict__ B,
    const float* __restrict__ bias,
    unsigned short* __restrict__ Qo,
    unsigned short* __restrict__ Ko,
    unsigned short* __restrict__ Vo)
{
  __shared__ unsigned short sm[4][12288];
  int id  = blockIdx.x;
  int swz = (id & 7) * (gridDim.x >> 3) + (id >> 3);
  const int m0 = (swz / 48) * 256, n0 = (swz % 48) * 128;
  GEMM_PRE();
  GEMM_MAIN();

  const int g4 = fg * 4;
#pragma unroll
  for (int n = 0; n < 4; ++n) {
    int ncol = n0 + wn * 64 + n * 16 + fr;
    float bv = bias[ncol];
    int head = ncol / 384;
    int rem  = ncol - head * 384;
    int wi   = rem >> 7;          // 0=q 1=k 2=v
    int d    = rem & 127;
    unsigned short* dst = (wi == 0) ? Qo : ((wi == 1) ? Ko : Vo);
#pragma unroll
    for (int m = 0; m < 4; ++m) {
#pragma unroll
      for (int j = 0; j < 4; ++j) {
        int r = m0 + wm * 64 + m * 16 + g4 + j;
        int s = r >> 1, bb = r & 1;
        float val = acc[m][n][j] + bv;
        if (wi == 0) val *= 0.08838834764831845f;   // fold 1/sqrt(128) into Q
        dst[(((size_t)(bb * NH + head)) * SEQ + s) * HD + d] = f2bf(val);
      }
    }
  }
}

// ---------------- dense GEMM: out = ctx @ w_dense^T + b (fp32 out) ----------------
// grid: 256 blocks (16 x 16), XCD-swizzled.
__global__ __launch_bounds__(512, 1) void dense_gemm(
    const unsigned short* __restrict__ A,
    const unsigned short* __restrict__ B,
    const float* __restrict__ bias,
    float* __restrict__ out)
{
  __shared__ unsigned short sm[4][12288];
  int id  = blockIdx.x;
  int swz = (id & 7) * (gridDim.x >> 3) + (id >> 3);
  const int m0 = (swz / 16) * 256, n0 = (swz % 16) * 128;
  GEMM_PRE();
  GEMM_MAIN();

  const int g4 = fg * 4;
#pragma unroll
  for (int n = 0; n < 4; ++n) {
    int ncol = n0 + wn * 64 + n * 16 + fr;
    float bv = bias[ncol];
#pragma unroll
    for (int m = 0; m < 4; ++m) {
#pragma unroll
      for (int j = 0; j < 4; ++j) {
        int r = m0 + wm * 64 + m * 16 + g4 + j;
        out[(size_t)r * HID + ncol] = acc[m][n][j] + bv;
      }
    }
  }
}

// ---------------- causal flash attention, paired q-tiles ----------------
// grid (16 pairs, 32 bh); block 256 = 4 waves x 16 q-rows per tile.
// Block handles q-tiles {pair, 31-pair}: exactly 33 tile-computes each.
__global__ __launch_bounds__(256, 2) void attn_fwd(
    const unsigned short* __restrict__ Q,
    const unsigned short* __restrict__ K,
    const unsigned short* __restrict__ Vt,   // [bh][d][s]
    unsigned short* __restrict__ ctx)
{
  __shared__ unsigned short Ksh[2][64 * 128];   // swizzled granules, 16KB each
  __shared__ unsigned short Vsh[2][128 * 64];   // [d][key] swizzled, 16KB each
  __shared__ unsigned short Psh[4][16 * 72];    // per-wave P tile
  const int t = threadIdx.x, l = t & 63, w = t >> 6;
  int nwg = gridDim.x * gridDim.y;              // 512
  int id  = blockIdx.y * gridDim.x + blockIdx.x;
  int swz = (id & 7) * (nwg >> 3) + (id >> 3);
  const int pair = swz & 15;
  const int bh   = swz >> 4;
  const int qtA = pair, qtB = 31 - pair;
  const int fr = l & 15, fg = l >> 4;
  const size_t base  = (size_t)bh * SEQ * HD;
  const size_t vbase = (size_t)bh * HD * SEQ;

#define STAGE(BUF, KT) do {                                                   \
    const unsigned short* Kt_ = K + base + (size_t)((KT) * 64) * HD;          \
    _Pragma("unroll")                                                         \
    for (int i_ = 0; i_ < 4; ++i_) {                                          \
      int ch_  = w * 4 + i_;                                                  \
      int row_ = ch_ * 4 + (l >> 4);                                          \
      int c16_ = (l & 15) ^ (row_ & 7);                                       \
      gl_lds16(Kt_ + (size_t)row_ * HD + c16_ * 8, &Ksh[BUF][ch_ * 512]);     \
    }                                                                         \
    const unsigned short* Vg_ = Vt + vbase + (KT) * 64;                       \
    _Pragma("unroll")                                                         \
    for (int i_ = 0; i_ < 4; ++i_) {                                          \
      int ch_  = w * 4 + i_;                                                  \
      int row_ = ch_ * 8 + (l >> 3);                                          \
      int c16_ = (l & 7) ^ (row_ & 7);                                        \
      gl_lds16(Vg_ + (size_t)row_ * SEQ + c16_ * 8, &Vsh[BUF][ch_ * 512]);    \
    }                                                                         \
  } while (0)

#define COMPUTE_TILE(QF, OACC, MROW, LROW, QT) do {                           \
    f32x4 sacc[4] = {};                                                       \
    _Pragma("unroll")                                                         \
    for (int c_ = 0; c_ < 4; ++c_) {                                          \
      _Pragma("unroll")                                                       \
      for (int n_ = 0; n_ < 4; ++n_) {                                        \
        int krow = n_ * 16 + fr;                                              \
        int g_   = (c_ * 4 + fg) ^ (krow & 7);                                \
        bf16x8 kf = *(const bf16x8*)&Ksh[buf][krow * 128 + g_ * 8];           \
        sacc[n_] = mfma16(QF[c_], kf, sacc[n_]);                              \
      }                                                                       \
    }                                                                         \
    if (kt == (QT)) {                                                         \
      _Pragma("unroll")                                                       \
      for (int n_ = 0; n_ < 4; ++n_)                                          \
        _Pragma("unroll")                                                     \
        for (int j_ = 0; j_ < 4; ++j_)                                        \
          if (n_ * 16 + fr > w * 16 + fg * 4 + j_) sacc[n_][j_] = -1e30f;     \
    }                                                                         \
    float tm_[4];                                                             \
    _Pragma("unroll")                                                         \
    for (int j_ = 0; j_ < 4; ++j_) {                                          \
      float v0 = fmaxf(fmaxf(sacc[0][j_], sacc[1][j_]),                       \
                       fmaxf(sacc[2][j_], sacc[3][j_]));                      \
      v0 = fmaxf(v0, __shfl_xor(v0, 1));                                      \
      v0 = fmaxf(v0, __shfl_xor(v0, 2));                                      \
      v0 = fmaxf(v0, __shfl_xor(v0, 4));                                      \
      v0 = fmaxf(v0, __shfl_xor(v0, 8));                                      \
      tm_[j_] = v0;                                                           \
    }                                                                         \
    float sc_[4], ps_[4];                                                     \
    _Pragma("unroll")                                                         \
    for (int j_ = 0; j_ < 4; ++j_) {                                          \
      float mn_ = fmaxf(MROW[j_], tm_[j_]);                                   \
      sc_[j_] = exp2f((MROW[j_] - mn_) * LOG2E);                              \
      MROW[j_] = mn_;                                                         \
      ps_[j_] = 0.f;                                                          \
    }                                                                         \
    _Pragma("unroll")                                                         \
    for (int n_ = 0; n_ < 4; ++n_)                                            \
      _Pragma("unroll")                                                       \
      for (int j_ = 0; j_ < 4; ++j_) {                                        \
        float p_ = exp2f((sacc[n_][j_] - MROW[j_]) * LOG2E);                  \
        sacc[n_][j_] = p_;                                                    \
        ps_[j_] += p_;                                                        \
      }                                                                       \
    _Pragma("unroll")                                                         \
    for (int j_ = 0; j_ < 4; ++j_) {                                          \
      float s_ = ps_[j_];                                                     \
      s_ += __shfl_xor(s_, 1);                                                \
      s_ += __shfl_xor(s_, 2);                                                \
      s_ += __shfl_xor(s_, 4);                                                \
      s_ += __shfl_xor(s_, 8);                                                \
      LROW[j_] = LROW[j_] * sc_[j_] + s_;                                     \
    }                                                                         \
    _Pragma("unroll")                                                         \
    for (int n_ = 0; n_ < 8; ++n_)                                            \
      _Pragma("unroll")                                                       \
      for (int j_ = 0; j_ < 4; ++j_)                                          \
        OACC[n_][j_] *= sc_[j_];                                              \
    _Pragma("unroll")                                                         \
    for (int n_ = 0; n_ < 4; ++n_)                                            \
      _Pragma("unroll")                                                       \
      for (int j_ = 0; j_ < 4; ++j_)                                          \
        Psh[w][(fg * 4 + j_) * 72 + n_ * 16 + fr] = f2bf(sacc[n_][j_]);       \
    _Pragma("unroll")                                                         \
    for (int ks_ = 0; ks_ < 2; ++ks_) {                                       \
      bf16x8 pf = *(const bf16x8*)&Psh[w][fr * 72 + ks_ * 32 + fg * 8];       \
      _Pragma("unroll")                                                       \
      for (int n_ = 0; n_ < 8; ++n_) {                                        \
        int vrow = n_ * 16 + fr;                                              \
        int g_   = (ks_ * 4 + fg) ^ (vrow & 7);                               \
        bf16x8 vf = *(const bf16x8*)&Vsh[buf][vrow * 64 + g_ * 8];            \
        OACC[n_] = mfma16(pf, vf, OACC[n_]);                                  \
      }                                                                       \
    }                                                                         \
  } while (0)

  // Q fragments for both tiles (scale folded in at QKV epilogue)
  bf16x8 qfA[4], qfB[4];
  {
    const unsigned short* qpA = Q + base + (size_t)(qtA * 64 + w * 16 + fr) * HD + fg * 8;
    const unsigned short* qpB = Q + base + (size_t)(qtB * 64 + w * 16 + fr) * HD + fg * 8;
#pragma unroll
    for (int c = 0; c < 4; ++c) {
      qfA[c] = *(const bf16x8*)(qpA + c * 32);
      qfB[c] = *(const bf16x8*)(qpB + c * 32);
    }
  }
  f32x4 oaccA[8] = {}, oaccB[8] = {};
  float mA[4] = {-1e30f, -1e30f, -1e30f, -1e30f};
  float mB[4] = {-1e30f, -1e30f, -1e30f, -1e30f};
  float lA[4] = {0.f, 0.f, 0.f, 0.f};
  float lB[4] = {0.f, 0.f, 0.f, 0.f};

  STAGE(0, 0);
  __syncthreads();
  int buf = 0;
  for (int kt = 0; kt <= qtB; ++kt) {
    if (kt < qtB) STAGE(buf ^ 1, kt + 1);       // prefetch hides under compute
    COMPUTE_TILE(qfB, oaccB, mB, lB, qtB);
    if (kt <= qtA) COMPUTE_TILE(qfA, oaccA, mA, lA, qtA);
    __syncthreads();                            // drains vmcnt -> next buf ready
    buf ^= 1;
  }

  const int bb = bh >> 4, h = bh & 15;
#define WRITE_CTX(OACC, LROW, QT) do {                                        \
    _Pragma("unroll")                                                         \
    for (int n_ = 0; n_ < 8; ++n_)                                            \
      _Pragma("unroll")                                                       \
      for (int j_ = 0; j_ < 4; ++j_) {                                        \
        int qrow = (QT) * 64 + w * 16 + fg * 4 + j_;                          \
        float val = OACC[n_][j_] / LROW[j_];                                  \
        ctx[((size_t)(qrow * BATCH + bb)) * HID + h * HD + n_ * 16 + fr] =    \
            f2bf(val);                                                        \
      }                                                                       \
  } while (0)
  WRITE_CTX(oaccA, lA, qtA);
  WRITE_CTX(oaccB, lB, qtB);
#undef STAGE
#undef COMPUTE_TILE
#undef WRITE_CTX
}

// ---------------- launcher ----------------
extern "C" void kernel_launch(void* const* d_in, const int* in_sizes, int n_in,
                              void* d_out, int out_size, void* d_ws, size_t ws_size,
                              hipStream_t stream) {
  const float* hs      = (const float*)d_in[0];
  const float* w_qkv   = (const float*)d_in[1];
  const float* b_qkv   = (const float*)d_in[2];
  const float* w_dense = (const float*)d_in[3];
  const float* b_dense = (const float*)d_in[4];
  float* out = (float*)d_out;

  unsigned short* hsb = (unsigned short*)d_ws;              // 8.4M shorts
  unsigned short* wqb = hsb + (size_t)MTOT * HID;
  unsigned short* wdb = wqb + (size_t)NQKV * HID;
  unsigned short* q   = wdb + (size_t)HID * HID;
  unsigned short* k   = q   + (size_t)MTOT * HID;
  unsigned short* v   = k   + (size_t)MTOT * HID;
  unsigned short* ctx = v   + (size_t)MTOT * HID;
  unsigned short* vt  = hsb;   // alias: hsb is dead after qkv_gemm, vt written before attn

  cvt_f32_bf16<<<2048, 256, 0, stream>>>(hs,      hsb, (MTOT * HID) / 4);
  cvt_f32_bf16<<<2048, 256, 0, stream>>>(w_qkv,   wqb, (NQKV * HID) / 4);
  cvt_f32_bf16<<<1024, 256, 0, stream>>>(w_dense, wdb, (HID * HID) / 4);

  qkv_gemm<<<dim3((MTOT / 256) * (NQKV / 128)), 512, 0, stream>>>(hsb, wqb, b_qkv, q, k, v);
  transpose_v<<<dim3(SEQ / 64, HD / 64, BATCH * NH), 256, 0, stream>>>(v, vt);
  attn_fwd<<<dim3(16, 32), 256, 0, stream>>>(q, k, vt, ctx);
  dense_gemm<<<dim3((MTOT / 256) * (HID / 128)), 512, 0, stream>>>(ctx, wdb, b_dense, out);
}

// Round 4
// 274.712 us; speedup vs baseline: 1.8112x; 1.0666x over previous
//
#include <hip/hip_runtime.h>
#include <stdint.h>
#include <stddef.h>

// ---------------- problem constants ----------------
#define SEQ   2048
#define BATCH 2
#define HID   2048
#define NH    16
#define HD    128
#define MTOT  (SEQ*BATCH)   // 4096
#define NQKV  (3*HID)       // 6144
#define KDIM  HID           // 2048
#define LOG2E 1.4426950408889634f

#define BK64    64
#define NT64    (KDIM/BK64)   // 32

typedef short  bf16x8 __attribute__((ext_vector_type(8)));  // 8 bf16 in 4 VGPRs
typedef float  f32x4  __attribute__((ext_vector_type(4)));

__device__ __forceinline__ unsigned short f2bf(float f) {
  union { float f; uint32_t u; } a; a.f = f;
  uint32_t r = a.u + 0x7fffu + ((a.u >> 16) & 1u);   // RNE
  return (unsigned short)(r >> 16);
}

__device__ __forceinline__ f32x4 mfma16(bf16x8 a, bf16x8 b, f32x4 c) {
  return __builtin_amdgcn_mfma_f32_16x16x32_bf16(a, b, c, 0, 0, 0);
}

// async global->LDS, 16B per lane; LDS dest = wave-uniform base + lane*16
__device__ __forceinline__ void gl_lds16(const unsigned short* g, unsigned short* l) {
  __builtin_amdgcn_global_load_lds(
      (const __attribute__((address_space(1))) void*)g,
      (__attribute__((address_space(3))) void*)l, 16, 0, 0);
}

// ---------------- fp32 -> bf16 convert ----------------
__global__ void cvt_f32_bf16(const float* __restrict__ in,
                             unsigned short* __restrict__ out, int n4) {
  int i = blockIdx.x * blockDim.x + threadIdx.x;
  int stride = gridDim.x * blockDim.x;
  for (; i < n4; i += stride) {
    float4 f = reinterpret_cast<const float4*>(in)[i];
    ushort4 o;
    o.x = f2bf(f.x); o.y = f2bf(f.y); o.z = f2bf(f.z); o.w = f2bf(f.w);
    reinterpret_cast<ushort4*>(out)[i] = o;
  }
}

// ---------------- V transpose: [bh][s][d] -> [bh][d][s] ----------------
__global__ __launch_bounds__(256) void transpose_v(
    const unsigned short* __restrict__ V, unsigned short* __restrict__ Vt) {
  __shared__ unsigned short tile[64][72];
  const int t  = threadIdx.x;
  const int bh = blockIdx.z;
  const int s0 = blockIdx.x * 64;
  const int d0 = blockIdx.y * 64;
  const size_t vb = (size_t)bh * SEQ * HD;
  const size_t tb = (size_t)bh * HD * SEQ;
#pragma unroll
  for (int p = 0; p < 2; ++p) {
    int r = p * 32 + (t >> 3);
    *(uint4*)&tile[r][(t & 7) * 8] =
        *(const uint4*)&V[vb + (size_t)(s0 + r) * HD + d0 + (t & 7) * 8];
  }
  __syncthreads();
#pragma unroll
  for (int p = 0; p < 2; ++p) {
    int dr = p * 32 + (t >> 3);
    int sc = (t & 7) * 8;
    unsigned short tmp[8];
#pragma unroll
    for (int e = 0; e < 8; ++e) tmp[e] = tile[sc + e][dr];
    *(uint4*)&Vt[tb + (size_t)(d0 + dr) * SEQ + s0 + sc] = *(const uint4*)tmp;
  }
}

// =====================================================================
// Deep-pipelined GEMM (BM=256, BN=128, BK=64, 512 thr, 8 waves 4x2).
// LDS: 3 buffers x 48KB (A 32KB + B 16KB), rows of 64 bf16 = 128B = all
// 32 banks. Swizzle (involution, 16B granules): LDS[r][g] holds global
// granule g ^ (r&7)  -> frag reads land 2 lanes/bank-quad = conflict-free.
// Staged via global_load_lds: chunk = 8 rows = 1KB; lane l -> row l>>3,
// LDS granule l&7, source granule (l&7)^(l>>3) (same 128B row segment).
// Pipeline: depth-2 prefetch, steady-state s_waitcnt vmcnt(6) (6 loads/
// wave/tile), two barriers per K-tile, 32 MFMA between them.
// =====================================================================

#define GEMM_PRE()                                                            \
  const int t = threadIdx.x, l = t & 63, w = t >> 6;                          \
  const int wm = w >> 1, wn = w & 1;                                          \
  const int fr = l & 15, fg = l >> 4;                                         \
  const int fx = fr & 7;                                                      \
  const int srow = l >> 3;                                                    \
  const int sgr  = ((l & 7) ^ srow) * 8;                                      \
  const unsigned short* Aw = A + (size_t)(m0 + w * 32 + srow) * KDIM + sgr;   \
  const unsigned short* Bw = B + (size_t)(n0 + w * 16 + srow) * KDIM + sgr;   \
  unsigned short* smb = &sm[0][0];                                            \
  const int a0 = (wm * 64 + fr) * 64 + ((fg ^ fx) * 8);                       \
  const int a1 = (wm * 64 + fr) * 64 + (((4 + fg) ^ fx) * 8);                 \
  const int b0 = 16384 + (wn * 64 + fr) * 64 + ((fg ^ fx) * 8);               \
  const int b1 = 16384 + (wn * 64 + fr) * 64 + (((4 + fg) ^ fx) * 8);         \
  f32x4 acc[4][4] = {};

#define STAGE_AB(KT) do {                                                     \
    unsigned short* dst = &smb[((KT) % 3) * 24576];                           \
    const unsigned short* ap = Aw + (size_t)(KT) * BK64;                      \
    gl_lds16(ap,                    &dst[(w * 4 + 0) * 512]);                 \
    gl_lds16(ap + 8  * KDIM,        &dst[(w * 4 + 1) * 512]);                 \
    gl_lds16(ap + 16 * KDIM,        &dst[(w * 4 + 2) * 512]);                 \
    gl_lds16(ap + 24 * KDIM,        &dst[(w * 4 + 3) * 512]);                 \
    const unsigned short* bp = Bw + (size_t)(KT) * BK64;                      \
    gl_lds16(bp,                    &dst[16384 + (w * 2 + 0) * 512]);         \
    gl_lds16(bp + 8 * KDIM,         &dst[16384 + (w * 2 + 1) * 512]);         \
  } while (0)

#define GEMM_BODY(KT, VM, DOSTAGE) do {                                       \
    const unsigned short* sb = &smb[((KT) % 3) * 24576];                      \
    if (DOSTAGE) STAGE_AB((KT) + 2);                                          \
    bf16x8 af0[4], af1[4], bg0[4], bg1[4];                                    \
    _Pragma("unroll")                                                         \
    for (int m_ = 0; m_ < 4; ++m_) {                                          \
      af0[m_] = *(const bf16x8*)&sb[a0 + m_ * 1024];                          \
      af1[m_] = *(const bf16x8*)&sb[a1 + m_ * 1024];                          \
    }                                                                         \
    _Pragma("unroll")                                                         \
    for (int n_ = 0; n_ < 4; ++n_) {                                          \
      bg0[n_] = *(const bf16x8*)&sb[b0 + n_ * 1024];                          \
      bg1[n_] = *(const bf16x8*)&sb[b1 + n_ * 1024];                          \
    }                                                                         \
    asm volatile("s_waitcnt vmcnt(" #VM ")" ::: "memory");                    \
    asm volatile("s_barrier" ::: "memory");                                   \
    asm volatile("s_waitcnt lgkmcnt(0)" ::: "memory");                        \
    __builtin_amdgcn_sched_barrier(0);                                        \
    __builtin_amdgcn_s_setprio(1);                                            \
    _Pragma("unroll")                                                         \
    for (int m_ = 0; m_ < 4; ++m_)                                            \
      _Pragma("unroll")                                                       \
      for (int n_ = 0; n_ < 4; ++n_)                                          \
        acc[m_][n_] = mfma16(af0[m_], bg0[n_], acc[m_][n_]);                  \
    _Pragma("unroll")                                                         \
    for (int m_ = 0; m_ < 4; ++m_)                                            \
      _Pragma("unroll")                                                       \
      for (int n_ = 0; n_ < 4; ++n_)                                          \
        acc[m_][n_] = mfma16(af1[m_], bg1[n_], acc[m_][n_]);                  \
    __builtin_amdgcn_sched_barrier(0);                                        \
    __builtin_amdgcn_s_setprio(0);                                            \
    asm volatile("s_barrier" ::: "memory");                                   \
  } while (0)

#define GEMM_MAIN()                                                           \
  STAGE_AB(0); STAGE_AB(1);                                                   \
  asm volatile("s_waitcnt vmcnt(6)" ::: "memory");                            \
  asm volatile("s_barrier" ::: "memory");                                     \
  _Pragma("unroll 1")                                                         \
  for (int kt = 0; kt < NT64 - 2; ++kt)                                       \
    GEMM_BODY(kt, 6, 1);                                                      \
  GEMM_BODY(NT64 - 2, 0, 0);                                                  \
  GEMM_BODY(NT64 - 1, 0, 0);

// ---------------- QKV GEMM + scatter epilogue ----------------
// grid: 768 blocks (16 m-blocks x 48 n-blocks), XCD-swizzled.
__global__ __launch_bounds__(512, 1) void qkv_gemm(
    const unsigned short* __restrict__ A,
    const unsigned short* __restrict__ B,
    const float* __restrict__ bias,
    unsigned short* __restrict__ Qo,
    unsigned short* __restrict__ Ko,
    unsigned short* __restrict__ Vo)
{
  __shared__ unsigned short sm[3][24576];   // 144KB
  int id  = blockIdx.x;
  int swz = (id & 7) * (gridDim.x >> 3) + (id >> 3);
  const int m0 = (swz / 48) * 256, n0 = (swz % 48) * 128;
  GEMM_PRE();
  GEMM_MAIN();

  const int g4 = fg * 4;
#pragma unroll
  for (int n = 0; n < 4; ++n) {
    int ncol = n0 + wn * 64 + n * 16 + fr;
    float bv = bias[ncol];
    int head = ncol / 384;
    int rem  = ncol - head * 384;
    int wi   = rem >> 7;          // 0=q 1=k 2=v
    int d    = rem & 127;
    unsigned short* dst = (wi == 0) ? Qo : ((wi == 1) ? Ko : Vo);
#pragma unroll
    for (int m = 0; m < 4; ++m) {
#pragma unroll
      for (int j = 0; j < 4; ++j) {
        int r = m0 + wm * 64 + m * 16 + g4 + j;
        int s = r >> 1, bb = r & 1;
        float val = acc[m][n][j] + bv;
        if (wi == 0) val *= 0.08838834764831845f;   // fold 1/sqrt(128) into Q
        dst[(((size_t)(bb * NH + head)) * SEQ + s) * HD + d] = f2bf(val);
      }
    }
  }
}

// ---------------- dense GEMM: out = ctx @ w_dense^T + b (fp32 out) ----------------
// grid: 256 blocks (16 x 16), XCD-swizzled.
__global__ __launch_bounds__(512, 1) void dense_gemm(
    const unsigned short* __restrict__ A,
    const unsigned short* __restrict__ B,
    const float* __restrict__ bias,
    float* __restrict__ out)
{
  __shared__ unsigned short sm[3][24576];   // 144KB
  int id  = blockIdx.x;
  int swz = (id & 7) * (gridDim.x >> 3) + (id >> 3);
  const int m0 = (swz / 16) * 256, n0 = (swz % 16) * 128;
  GEMM_PRE();
  GEMM_MAIN();

  const int g4 = fg * 4;
#pragma unroll
  for (int n = 0; n < 4; ++n) {
    int ncol = n0 + wn * 64 + n * 16 + fr;
    float bv = bias[ncol];
#pragma unroll
    for (int m = 0; m < 4; ++m) {
#pragma unroll
      for (int j = 0; j < 4; ++j) {
        int r = m0 + wm * 64 + m * 16 + g4 + j;
        out[(size_t)r * HID + ncol] = acc[m][n][j] + bv;
      }
    }
  }
}

// ---------------- causal flash attention, paired q-tiles ----------------
// grid (16 pairs, 32 bh); block 256 = 4 waves x 16 q-rows per tile.
// Block handles q-tiles {pair, 31-pair}: exactly 33 tile-computes each.
__global__ __launch_bounds__(256, 2) void attn_fwd(
    const unsigned short* __restrict__ Q,
    const unsigned short* __restrict__ K,
    const unsigned short* __restrict__ Vt,   // [bh][d][s]
    unsigned short* __restrict__ ctx)
{
  __shared__ unsigned short Ksh[2][64 * 128];   // swizzled granules, 16KB each
  __shared__ unsigned short Vsh[2][128 * 64];   // [d][key] swizzled, 16KB each
  __shared__ unsigned short Psh[4][16 * 72];    // per-wave P tile
  const int t = threadIdx.x, l = t & 63, w = t >> 6;
  int nwg = gridDim.x * gridDim.y;              // 512
  int id  = blockIdx.y * gridDim.x + blockIdx.x;
  int swz = (id & 7) * (nwg >> 3) + (id >> 3);
  const int pair = swz & 15;
  const int bh   = swz >> 4;
  const int qtA = pair, qtB = 31 - pair;
  const int fr = l & 15, fg = l >> 4;
  const size_t base  = (size_t)bh * SEQ * HD;
  const size_t vbase = (size_t)bh * HD * SEQ;

#define STAGE(BUF, KT) do {                                                   \
    const unsigned short* Kt_ = K + base + (size_t)((KT) * 64) * HD;          \
    _Pragma("unroll")                                                         \
    for (int i_ = 0; i_ < 4; ++i_) {                                          \
      int ch_  = w * 4 + i_;                                                  \
      int row_ = ch_ * 4 + (l >> 4);                                          \
      int c16_ = (l & 15) ^ (row_ & 7);                                       \
      gl_lds16(Kt_ + (size_t)row_ * HD + c16_ * 8, &Ksh[BUF][ch_ * 512]);     \
    }                                                                         \
    const unsigned short* Vg_ = Vt + vbase + (KT) * 64;                       \
    _Pragma("unroll")                                                         \
    for (int i_ = 0; i_ < 4; ++i_) {                                          \
      int ch_  = w * 4 + i_;                                                  \
      int row_ = ch_ * 8 + (l >> 3);                                          \
      int c16_ = (l & 7) ^ (row_ & 7);                                        \
      gl_lds16(Vg_ + (size_t)row_ * SEQ + c16_ * 8, &Vsh[BUF][ch_ * 512]);    \
    }                                                                         \
  } while (0)

#define COMPUTE_TILE(QF, OACC, MROW, LROW, QT) do {                           \
    f32x4 sacc[4] = {};                                                       \
    _Pragma("unroll")                                                         \
    for (int c_ = 0; c_ < 4; ++c_) {                                          \
      _Pragma("unroll")                                                       \
      for (int n_ = 0; n_ < 4; ++n_) {                                        \
        int krow = n_ * 16 + fr;                                              \
        int g_   = (c_ * 4 + fg) ^ (krow & 7);                                \
        bf16x8 kf = *(const bf16x8*)&Ksh[buf][krow * 128 + g_ * 8];           \
        sacc[n_] = mfma16(QF[c_], kf, sacc[n_]);                              \
      }                                                                       \
    }                                                                         \
    if (kt == (QT)) {                                                         \
      _Pragma("unroll")                                                       \
      for (int n_ = 0; n_ < 4; ++n_)                                          \
        _Pragma("unroll")                                                     \
        for (int j_ = 0; j_ < 4; ++j_)                                        \
          if (n_ * 16 + fr > w * 16 + fg * 4 + j_) sacc[n_][j_] = -1e30f;     \
    }                                                                         \
    float tm_[4];                                                             \
    _Pragma("unroll")                                                         \
    for (int j_ = 0; j_ < 4; ++j_) {                                          \
      float v0 = fmaxf(fmaxf(sacc[0][j_], sacc[1][j_]),                       \
                       fmaxf(sacc[2][j_], sacc[3][j_]));                      \
      v0 = fmaxf(v0, __shfl_xor(v0, 1));                                      \
      v0 = fmaxf(v0, __shfl_xor(v0, 2));                                      \
      v0 = fmaxf(v0, __shfl_xor(v0, 4));                                      \
      v0 = fmaxf(v0, __shfl_xor(v0, 8));                                      \
      tm_[j_] = v0;                                                           \
    }                                                                         \
    float sc_[4], ps_[4];                                                     \
    _Pragma("unroll")                                                         \
    for (int j_ = 0; j_ < 4; ++j_) {                                          \
      float mn_ = fmaxf(MROW[j_], tm_[j_]);                                   \
      sc_[j_] = exp2f((MROW[j_] - mn_) * LOG2E);                              \
      MROW[j_] = mn_;                                                         \
      ps_[j_] = 0.f;                                                          \
    }                                                                         \
    _Pragma("unroll")                                                         \
    for (int n_ = 0; n_ < 4; ++n_)                                            \
      _Pragma("unroll")                                                       \
      for (int j_ = 0; j_ < 4; ++j_) {                                        \
        float p_ = exp2f((sacc[n_][j_] - MROW[j_]) * LOG2E);                  \
        sacc[n_][j_] = p_;                                                    \
        ps_[j_] += p_;                                                        \
      }                                                                       \
    _Pragma("unroll")                                                         \
    for (int j_ = 0; j_ < 4; ++j_) {                                          \
      float s_ = ps_[j_];                                                     \
      s_ += __shfl_xor(s_, 1);                                                \
      s_ += __shfl_xor(s_, 2);                                                \
      s_ += __shfl_xor(s_, 4);                                                \
      s_ += __shfl_xor(s_, 8);                                                \
      LROW[j_] = LROW[j_] * sc_[j_] + s_;                                     \
    }                                                                         \
    _Pragma("unroll")                                                         \
    for (int n_ = 0; n_ < 8; ++n_)                                            \
      _Pragma("unroll")                                                       \
      for (int j_ = 0; j_ < 4; ++j_)                                          \
        OACC[n_][j_] *= sc_[j_];                                              \
    _Pragma("unroll")                                                         \
    for (int n_ = 0; n_ < 4; ++n_)                                            \
      _Pragma("unroll")                                                       \
      for (int j_ = 0; j_ < 4; ++j_)                                          \
        Psh[w][(fg * 4 + j_) * 72 + n_ * 16 + fr] = f2bf(sacc[n_][j_]);       \
    _Pragma("unroll")                                                         \
    for (int ks_ = 0; ks_ < 2; ++ks_) {                                       \
      bf16x8 pf = *(const bf16x8*)&Psh[w][fr * 72 + ks_ * 32 + fg * 8];       \
      _Pragma("unroll")                                                       \
      for (int n_ = 0; n_ < 8; ++n_) {                                        \
        int vrow = n_ * 16 + fr;                                              \
        int g_   = (ks_ * 4 + fg) ^ (vrow & 7);                               \
        bf16x8 vf = *(const bf16x8*)&Vsh[buf][vrow * 64 + g_ * 8];            \
        OACC[n_] = mfma16(pf, vf, OACC[n_]);                                  \
      }                                                                       \
    }                                                                         \
  } while (0)

  // Q fragments for both tiles (scale folded in at QKV epilogue)
  bf16x8 qfA[4], qfB[4];
  {
    const unsigned short* qpA = Q + base + (size_t)(qtA * 64 + w * 16 + fr) * HD + fg * 8;
    const unsigned short* qpB = Q + base + (size_t)(qtB * 64 + w * 16 + fr) * HD + fg * 8;
#pragma unroll
    for (int c = 0; c < 4; ++c) {
      qfA[c] = *(const bf16x8*)(qpA + c * 32);
      qfB[c] = *(const bf16x8*)(qpB + c * 32);
    }
  }
  f32x4 oaccA[8] = {}, oaccB[8] = {};
  float mA[4] = {-1e30f, -1e30f, -1e30f, -1e30f};
  float mB[4] = {-1e30f, -1e30f, -1e30f, -1e30f};
  float lA[4] = {0.f, 0.f, 0.f, 0.f};
  float lB[4] = {0.f, 0.f, 0.f, 0.f};

  STAGE(0, 0);
  __syncthreads();
  int buf = 0;
  for (int kt = 0; kt <= qtB; ++kt) {
    if (kt < qtB) STAGE(buf ^ 1, kt + 1);       // prefetch hides under compute
    COMPUTE_TILE(qfB, oaccB, mB, lB, qtB);
    if (kt <= qtA) COMPUTE_TILE(qfA, oaccA, mA, lA, qtA);
    __syncthreads();                            // drains vmcnt -> next buf ready
    buf ^= 1;
  }

  const int bb = bh >> 4, h = bh & 15;
#define WRITE_CTX(OACC, LROW, QT) do {                                        \
    _Pragma("unroll")                                                         \
    for (int n_ = 0; n_ < 8; ++n_)                                            \
      _Pragma("unroll")                                                       \
      for (int j_ = 0; j_ < 4; ++j_) {                                        \
        int qrow = (QT) * 64 + w * 16 + fg * 4 + j_;                          \
        float val = OACC[n_][j_] / LROW[j_];                                  \
        ctx[((size_t)(qrow * BATCH + bb)) * HID + h * HD + n_ * 16 + fr] =    \
            f2bf(val);                                                        \
      }                                                                       \
  } while (0)
  WRITE_CTX(oaccA, lA, qtA);
  WRITE_CTX(oaccB, lB, qtB);
#undef STAGE
#undef COMPUTE_TILE
#undef WRITE_CTX
}

// ---------------- launcher ----------------
extern "C" void kernel_launch(void* const* d_in, const int* in_sizes, int n_in,
                              void* d_out, int out_size, void* d_ws, size_t ws_size,
                              hipStream_t stream) {
  const float* hs      = (const float*)d_in[0];
  const float* w_qkv   = (const float*)d_in[1];
  const float* b_qkv   = (const float*)d_in[2];
  const float* w_dense = (const float*)d_in[3];
  const float* b_dense = (const float*)d_in[4];
  float* out = (float*)d_out;

  unsigned short* hsb = (unsigned short*)d_ws;              // 8.4M shorts
  unsigned short* wqb = hsb + (size_t)MTOT * HID;
  unsigned short* wdb = wqb + (size_t)NQKV * HID;
  unsigned short* q   = wdb + (size_t)HID * HID;
  unsigned short* k   = q   + (size_t)MTOT * HID;
  unsigned short* v   = k   + (size_t)MTOT * HID;
  unsigned short* ctx = v   + (size_t)MTOT * HID;
  unsigned short* vt  = hsb;   // alias: hsb is dead after qkv_gemm, vt written before attn

  cvt_f32_bf16<<<2048, 256, 0, stream>>>(hs,      hsb, (MTOT * HID) / 4);
  cvt_f32_bf16<<<2048, 256, 0, stream>>>(w_qkv,   wqb, (NQKV * HID) / 4);
  cvt_f32_bf16<<<1024, 256, 0, stream>>>(w_dense, wdb, (HID * HID) / 4);

  qkv_gemm<<<dim3((MTOT / 256) * (NQKV / 128)), 512, 0, stream>>>(hsb, wqb, b_qkv, q, k, v);
  transpose_v<<<dim3(SEQ / 64, HD / 64, BATCH * NH), 256, 0, stream>>>(v, vt);
  attn_fwd<<<dim3(16, 32), 256, 0, stream>>>(q, k, vt, ctx);
  dense_gemm<<<dim3((MTOT / 256) * (HID / 128)), 512, 0, stream>>>(ctx, wdb, b_dense, out);
}